// Round 5
// baseline (423.941 us; speedup 1.0000x reference)
//
#include <hip/hip_runtime.h>

#define N_NODES 50000
#define N_EDGES 800000
#define SCAN_NB ((N_NODES + 255) / 256)

// ---------- CSR build ----------

__global__ __launch_bounds__(256) void count_kernel(const int* __restrict__ dst,
                                                    int* __restrict__ cnt, int nedges) {
    int e = blockIdx.x * 256 + threadIdx.x;
    if (e < nedges) atomicAdd(&cnt[dst[e]], 1);
}

__device__ __forceinline__ int wave_incl_scan(int v, int lane) {
#pragma unroll
    for (int off = 1; off < 64; off <<= 1) {
        int t = __shfl_up(v, off, 64);
        if (lane >= off) v += t;
    }
    return v;
}

__global__ __launch_bounds__(256) void scanA_kernel(const int* __restrict__ cnt,
                                                    int* __restrict__ partials, int n) {
    const int i = blockIdx.x * 256 + threadIdx.x;
    const int lane = threadIdx.x & 63;
    const int w = threadIdx.x >> 6;
    int v = (i < n) ? cnt[i] : 0;
    int s = wave_incl_scan(v, lane);
    __shared__ int ws[4];
    if (lane == 63) ws[w] = s;
    __syncthreads();
    if (threadIdx.x == 0) partials[blockIdx.x] = ws[0] + ws[1] + ws[2] + ws[3];
}

__global__ __launch_bounds__(256) void scanB_kernel(int* __restrict__ partials, int nb) {
    const int i = threadIdx.x;
    const int lane = i & 63;
    const int w = i >> 6;
    int v = (i < nb) ? partials[i] : 0;
    int s = wave_incl_scan(v, lane);
    __shared__ int ws[4];
    if (lane == 63) ws[w] = s;
    __syncthreads();
    int add = 0;
#pragma unroll
    for (int k = 0; k < 4; ++k)
        if (k < w) add += ws[k];
    if (i < nb) partials[i] = s + add - v;  // exclusive
}

__global__ __launch_bounds__(256) void scanC_kernel(const int* __restrict__ cnt,
                                                    const int* __restrict__ partials,
                                                    int* __restrict__ rowptr,
                                                    int* __restrict__ cursor,
                                                    float* __restrict__ norm, int n) {
    const int i = blockIdx.x * 256 + threadIdx.x;
    const int lane = threadIdx.x & 63;
    const int w = threadIdx.x >> 6;
    int v = (i < n) ? cnt[i] : 0;
    int s = wave_incl_scan(v, lane);
    __shared__ int ws[4];
    if (lane == 63) ws[w] = s;
    __syncthreads();
    int add = partials[blockIdx.x];
#pragma unroll
    for (int k = 0; k < 4; ++k)
        if (k < w) add += ws[k];
    if (i < n) {
        int excl = s + add - v;
        rowptr[i] = excl;
        cursor[i] = excl;
        norm[i] = v > 0 ? rsqrtf((float)v) : 0.0f;
        if (i == n - 1) rowptr[n] = excl + v;
    }
}

__global__ __launch_bounds__(256) void fill_kernel(const int* __restrict__ src,
                                                   const int* __restrict__ dst,
                                                   int* __restrict__ cursor,
                                                   int* __restrict__ esrc, int nedges) {
    int e = blockIdx.x * 256 + threadIdx.x;
    if (e < nedges) {
        int pos = atomicAdd(&cursor[dst[e]], 1);
        esrc[pos] = src[e];
    }
}

// ---------- GEMM with output row-scale, W staged in LDS ----------
// C_sliced[s][r][c] = norm[r] * sum_k X[r,k] * W[k, s*16+c]
// Output layout: F/16 slabs of [nrows x 16] floats (slice-major) for L2-local gathers.
template <int OUT>
__global__ __launch_bounds__(256) void gemm_rownorm(const float* __restrict__ X,
                                                    const float* __restrict__ W,
                                                    const float* __restrict__ norm,
                                                    float* __restrict__ C, int nrows) {
    __shared__ float Wlds[128 * OUT];

    const int t = threadIdx.x;

    constexpr int NSTAGE = (128 * OUT) / (256 * 4);
    {
        const float4* __restrict__ Wg = reinterpret_cast<const float4*>(W);
        float4* Wl = reinterpret_cast<float4*>(Wlds);
#pragma unroll
        for (int s = 0; s < NSTAGE; ++s) {
            int idx = s * 256 + t;
            Wl[idx] = Wg[idx];
        }
    }
    __syncthreads();

    const int tc = t & 15;   // 16 col-groups (cols tc*4 .. tc*4+3, and +64 for OUT=128)
    const int tr = t >> 4;   // 16 row-groups
    const int rowbase = blockIdx.x * 128 + tr * 8;
    const int lastrow = nrows - 1;

    float4 acc0[8], acc1[8];
#pragma unroll
    for (int i = 0; i < 8; ++i) {
        acc0[i] = make_float4(0.f, 0.f, 0.f, 0.f);
        acc1[i] = make_float4(0.f, 0.f, 0.f, 0.f);
    }

    const float4* __restrict__ X4 = reinterpret_cast<const float4*>(X);
    int rIdx[8];
#pragma unroll
    for (int i = 0; i < 8; ++i) {
        int r = rowbase + i;
        rIdx[i] = r < lastrow ? r : lastrow;
    }

    for (int kk = 0; kk < 32; ++kk) {
        float4 x[8];
#pragma unroll
        for (int i = 0; i < 8; ++i) x[i] = X4[(size_t)rIdx[i] * 32 + kk];
#pragma unroll
        for (int j = 0; j < 4; ++j) {
            const int k = kk * 4 + j;
            const float4 w0 = *reinterpret_cast<const float4*>(&Wlds[k * OUT + tc * 4]);
            float4 w1;
            if constexpr (OUT == 128)
                w1 = *reinterpret_cast<const float4*>(&Wlds[k * OUT + 64 + tc * 4]);
#pragma unroll
            for (int i = 0; i < 8; ++i) {
                const float* xp = reinterpret_cast<const float*>(&x[i]);
                const float xs = xp[j];
                acc0[i].x += xs * w0.x;
                acc0[i].y += xs * w0.y;
                acc0[i].z += xs * w0.z;
                acc0[i].w += xs * w0.w;
                if constexpr (OUT == 128) {
                    acc1[i].x += xs * w1.x;
                    acc1[i].y += xs * w1.y;
                    acc1[i].z += xs * w1.z;
                    acc1[i].w += xs * w1.w;
                }
            }
        }
    }

    // Slice-major store: slab s is [nrows x 16] floats = nrows*4 float4.
    float4* __restrict__ C4 = reinterpret_cast<float4*>(C);
    const size_t slab = (size_t)nrows * 4;
    const int s0 = tc >> 2;        // slab for cols tc*4..tc*4+3
    const int w0i = tc & 3;        // float4 index within 16-col slab row
#pragma unroll
    for (int i = 0; i < 8; ++i) {
        int r = rowbase + i;
        if (r < nrows) {
            const float nm = norm[r];
            float4 o0 = acc0[i];
            o0.x *= nm; o0.y *= nm; o0.z *= nm; o0.w *= nm;
            C4[(size_t)s0 * slab + (size_t)r * 4 + w0i] = o0;
            if constexpr (OUT == 128) {
                float4 o1 = acc1[i];
                o1.x *= nm; o1.y *= nm; o1.z *= nm; o1.w *= nm;
                C4[(size_t)(s0 + 4) * slab + (size_t)r * 4 + w0i] = o1;
            }
        }
    }
}

// ---------- Column-sliced gather-aggregate + epilogue ----------
// Input feat is slice-major (F/16 slabs of [nnodes x 16] floats).
// slice = blockIdx.x % NSLICE -> one slab per XCD (L2-resident, 3.2 MB).
// Wave: 16 edges in parallel (4 lanes/edge, float4 = 16-col slice), shfl_xor reduce.
// Output row-major: out[node, slice*16 .. slice*16+15].
template <int F, bool RELU>
__global__ __launch_bounds__(256) void aggregate_sliced(const float* __restrict__ feat,
                                                        const int* __restrict__ rowptr,
                                                        const int* __restrict__ esrc,
                                                        const float* __restrict__ norm,
                                                        const float* __restrict__ b,
                                                        float* __restrict__ out,
                                                        int nnodes, int nchunks) {
    constexpr int NSLICE = F / 16;
    const int slice = blockIdx.x % NSLICE;
    const int chunk = blockIdx.x / NSLICE;
    const int span  = (nnodes + nchunks - 1) / nchunks;
    const int nbeg  = chunk * span;
    const int nend  = min(nnodes, nbeg + span);

    const int wave  = threadIdx.x >> 6;
    const int lane  = threadIdx.x & 63;
    const int g     = lane >> 2;   // edge-group 0..15
    const int lane4 = lane & 3;    // float4 within 16-col slice

    const float4* __restrict__ slab = reinterpret_cast<const float4*>(feat) + (size_t)slice * nnodes * 4;
    const float4 bb = reinterpret_cast<const float4*>(b)[slice * 4 + lane4];

    for (int node = nbeg + wave; node < nend; node += 4) {
        const int beg = rowptr[node];
        const int end = rowptr[node + 1];

        float4 acc = make_float4(0.f, 0.f, 0.f, 0.f);
        for (int e0 = beg; e0 < end; e0 += 16) {
            int e = e0 + g;
            int ec = e < end ? e : end - 1;
            int sIdx = esrc[ec];
            float4 v = slab[(size_t)sIdx * 4 + lane4];
            if (e < end) {
                acc.x += v.x; acc.y += v.y; acc.z += v.z; acc.w += v.w;
            }
        }
        // reduce across the 16 edge-groups (xor bits 2..5)
#pragma unroll
        for (int mask = 4; mask <= 32; mask <<= 1) {
            acc.x += __shfl_xor(acc.x, mask, 64);
            acc.y += __shfl_xor(acc.y, mask, 64);
            acc.z += __shfl_xor(acc.z, mask, 64);
            acc.w += __shfl_xor(acc.w, mask, 64);
        }
        if (lane < 4) {
            const float nm = norm[node];
            float4 o;
            o.x = acc.x * nm + bb.x;
            o.y = acc.y * nm + bb.y;
            o.z = acc.z * nm + bb.z;
            o.w = acc.w * nm + bb.w;
            if (RELU) {
                o.x = fmaxf(o.x, 0.f); o.y = fmaxf(o.y, 0.f);
                o.z = fmaxf(o.z, 0.f); o.w = fmaxf(o.w, 0.f);
            }
            reinterpret_cast<float4*>(out)[(size_t)node * (F / 4) + slice * 4 + lane4] = o;
        }
    }
}

extern "C" void kernel_launch(void* const* d_in, const int* in_sizes, int n_in,
                              void* d_out, int out_size, void* d_ws, size_t ws_size,
                              hipStream_t stream) {
    const float* features = (const float*)d_in[0];
    const int*   src      = (const int*)d_in[1];
    const int*   dst      = (const int*)d_in[2];
    const float* W1 = (const float*)d_in[3];
    const float* b1 = (const float*)d_in[4];
    const float* W2 = (const float*)d_in[5];
    const float* b2 = (const float*)d_in[6];
    const float* W3 = (const float*)d_in[7];
    const float* b3 = (const float*)d_in[8];
    float* out = (float*)d_out;

    auto align256 = [](size_t x) { return (x + 255) / 256 * 256; };
    char* ws = (char*)d_ws;
    size_t off = 0;
    float* norm     = (float*)(ws + off); off += align256((size_t)N_NODES * 4);
    int*   cnt      = (int*)(ws + off);   off += align256((size_t)N_NODES * 4);
    int*   cursor   = (int*)(ws + off);   off += align256((size_t)N_NODES * 4);
    int*   rowptr   = (int*)(ws + off);   off += align256(((size_t)N_NODES + 1) * 4);
    int*   partials = (int*)(ws + off);   off += align256((size_t)SCAN_NB * 4);
    int*   esrc     = (int*)(ws + off);   off += align256((size_t)N_EDGES * 4);
    float* buf0     = (float*)(ws + off); off += (size_t)N_NODES * 128 * 4;
    float* buf1     = (float*)(ws + off);

    const int gemm_blocks = (N_NODES + 127) / 128;
    const int edge_blocks = (N_EDGES + 255) / 256;
    const int chunks128 = 256;   // 256*8 = 2048 blocks
    const int chunks64  = 512;   // 512*4 = 2048 blocks

    // ---- CSR build + norm ----
    hipMemsetAsync(cnt, 0, (size_t)N_NODES * 4, stream);
    count_kernel<<<edge_blocks, 256, 0, stream>>>(dst, cnt, N_EDGES);
    scanA_kernel<<<SCAN_NB, 256, 0, stream>>>(cnt, partials, N_NODES);
    scanB_kernel<<<1, 256, 0, stream>>>(partials, SCAN_NB);
    scanC_kernel<<<SCAN_NB, 256, 0, stream>>>(cnt, partials, rowptr, cursor, norm, N_NODES);
    fill_kernel<<<edge_blocks, 256, 0, stream>>>(src, dst, cursor, esrc, N_EDGES);

    // ---- Layer 1 ----
    gemm_rownorm<128><<<gemm_blocks, 256, 0, stream>>>(features, W1, norm, buf0, N_NODES);
    aggregate_sliced<128, true><<<chunks128 * 8, 256, 0, stream>>>(buf0, rowptr, esrc, norm, b1, buf1, N_NODES, chunks128);

    // ---- Layer 2 ----
    gemm_rownorm<128><<<gemm_blocks, 256, 0, stream>>>(buf1, W2, norm, buf0, N_NODES);
    aggregate_sliced<128, true><<<chunks128 * 8, 256, 0, stream>>>(buf0, rowptr, esrc, norm, b2, buf1, N_NODES, chunks128);

    // ---- Layer 3 (64 cols) ----
    gemm_rownorm<64><<<gemm_blocks, 256, 0, stream>>>(buf1, W3, norm, buf0, N_NODES);
    aggregate_sliced<64, false><<<chunks64 * 4, 256, 0, stream>>>(buf0, rowptr, esrc, norm, b3, out, N_NODES, chunks64);
}

// Round 6
// 340.076 us; speedup vs baseline: 1.2466x; 1.2466x over previous
//
#include <hip/hip_runtime.h>

#define N_NODES 50000
#define N_EDGES 800000
#define SCAN_NB ((N_NODES + 255) / 256)

// ---------- CSR build ----------

__global__ __launch_bounds__(256) void count_kernel(const int* __restrict__ dst,
                                                    int* __restrict__ cnt, int nedges) {
    int e = blockIdx.x * 256 + threadIdx.x;
    if (e < nedges) atomicAdd(&cnt[dst[e]], 1);
}

__device__ __forceinline__ int wave_incl_scan(int v, int lane) {
#pragma unroll
    for (int off = 1; off < 64; off <<= 1) {
        int t = __shfl_up(v, off, 64);
        if (lane >= off) v += t;
    }
    return v;
}

__global__ __launch_bounds__(256) void scanA_kernel(const int* __restrict__ cnt,
                                                    int* __restrict__ partials, int n) {
    const int i = blockIdx.x * 256 + threadIdx.x;
    const int lane = threadIdx.x & 63;
    const int w = threadIdx.x >> 6;
    int v = (i < n) ? cnt[i] : 0;
    int s = wave_incl_scan(v, lane);
    __shared__ int ws[4];
    if (lane == 63) ws[w] = s;
    __syncthreads();
    if (threadIdx.x == 0) partials[blockIdx.x] = ws[0] + ws[1] + ws[2] + ws[3];
}

__global__ __launch_bounds__(256) void scanB_kernel(int* __restrict__ partials, int nb) {
    const int i = threadIdx.x;
    const int lane = i & 63;
    const int w = i >> 6;
    int v = (i < nb) ? partials[i] : 0;
    int s = wave_incl_scan(v, lane);
    __shared__ int ws[4];
    if (lane == 63) ws[w] = s;
    __syncthreads();
    int add = 0;
#pragma unroll
    for (int k = 0; k < 4; ++k)
        if (k < w) add += ws[k];
    if (i < nb) partials[i] = s + add - v;  // exclusive
}

__global__ __launch_bounds__(256) void scanC_kernel(const int* __restrict__ cnt,
                                                    const int* __restrict__ partials,
                                                    int* __restrict__ rowptr,
                                                    int* __restrict__ cursor,
                                                    float* __restrict__ norm, int n) {
    const int i = blockIdx.x * 256 + threadIdx.x;
    const int lane = threadIdx.x & 63;
    const int w = threadIdx.x >> 6;
    int v = (i < n) ? cnt[i] : 0;
    int s = wave_incl_scan(v, lane);
    __shared__ int ws[4];
    if (lane == 63) ws[w] = s;
    __syncthreads();
    int add = partials[blockIdx.x];
#pragma unroll
    for (int k = 0; k < 4; ++k)
        if (k < w) add += ws[k];
    if (i < n) {
        int excl = s + add - v;
        rowptr[i] = excl;
        cursor[i] = excl;
        norm[i] = v > 0 ? rsqrtf((float)v) : 0.0f;
        if (i == n - 1) rowptr[n] = excl + v;
    }
}

__global__ __launch_bounds__(256) void fill_kernel(const int* __restrict__ src,
                                                   const int* __restrict__ dst,
                                                   int* __restrict__ cursor,
                                                   int* __restrict__ esrc, int nedges) {
    int e = blockIdx.x * 256 + threadIdx.x;
    if (e < nedges) {
        int pos = atomicAdd(&cursor[dst[e]], 1);
        esrc[pos] = src[e];
    }
}

// ---------- GEMM with output row-scale, W staged in LDS ----------
// C_sliced[s][r][c] = norm[r] * sum_k X[r,k] * W[k, s*16+c]
// Output layout: F/16 slabs of [nrows x 16] floats (slice-major) for L2-local gathers.
template <int OUT>
__global__ __launch_bounds__(256) void gemm_rownorm(const float* __restrict__ X,
                                                    const float* __restrict__ W,
                                                    const float* __restrict__ norm,
                                                    float* __restrict__ C, int nrows) {
    __shared__ float Wlds[128 * OUT];

    const int t = threadIdx.x;

    constexpr int NSTAGE = (128 * OUT) / (256 * 4);
    {
        const float4* __restrict__ Wg = reinterpret_cast<const float4*>(W);
        float4* Wl = reinterpret_cast<float4*>(Wlds);
#pragma unroll
        for (int s = 0; s < NSTAGE; ++s) {
            int idx = s * 256 + t;
            Wl[idx] = Wg[idx];
        }
    }
    __syncthreads();

    const int tc = t & 15;   // 16 col-groups (cols tc*4 .. tc*4+3, and +64 for OUT=128)
    const int tr = t >> 4;   // 16 row-groups
    const int rowbase = blockIdx.x * 128 + tr * 8;
    const int lastrow = nrows - 1;

    float4 acc0[8], acc1[8];
#pragma unroll
    for (int i = 0; i < 8; ++i) {
        acc0[i] = make_float4(0.f, 0.f, 0.f, 0.f);
        acc1[i] = make_float4(0.f, 0.f, 0.f, 0.f);
    }

    const float4* __restrict__ X4 = reinterpret_cast<const float4*>(X);
    int rIdx[8];
#pragma unroll
    for (int i = 0; i < 8; ++i) {
        int r = rowbase + i;
        rIdx[i] = r < lastrow ? r : lastrow;
    }

    for (int kk = 0; kk < 32; ++kk) {
        float4 x[8];
#pragma unroll
        for (int i = 0; i < 8; ++i) x[i] = X4[(size_t)rIdx[i] * 32 + kk];
#pragma unroll
        for (int j = 0; j < 4; ++j) {
            const int k = kk * 4 + j;
            const float4 w0 = *reinterpret_cast<const float4*>(&Wlds[k * OUT + tc * 4]);
            float4 w1;
            if constexpr (OUT == 128)
                w1 = *reinterpret_cast<const float4*>(&Wlds[k * OUT + 64 + tc * 4]);
#pragma unroll
            for (int i = 0; i < 8; ++i) {
                const float* xp = reinterpret_cast<const float*>(&x[i]);
                const float xs = xp[j];
                acc0[i].x += xs * w0.x;
                acc0[i].y += xs * w0.y;
                acc0[i].z += xs * w0.z;
                acc0[i].w += xs * w0.w;
                if constexpr (OUT == 128) {
                    acc1[i].x += xs * w1.x;
                    acc1[i].y += xs * w1.y;
                    acc1[i].z += xs * w1.z;
                    acc1[i].w += xs * w1.w;
                }
            }
        }
    }

    // Slice-major store: slab s is [nrows x 16] floats = nrows*4 float4.
    float4* __restrict__ C4 = reinterpret_cast<float4*>(C);
    const size_t slab = (size_t)nrows * 4;
    const int s0 = tc >> 2;
    const int w0i = tc & 3;
#pragma unroll
    for (int i = 0; i < 8; ++i) {
        int r = rowbase + i;
        if (r < nrows) {
            const float nm = norm[r];
            float4 o0 = acc0[i];
            o0.x *= nm; o0.y *= nm; o0.z *= nm; o0.w *= nm;
            C4[(size_t)s0 * slab + (size_t)r * 4 + w0i] = o0;
            if constexpr (OUT == 128) {
                float4 o1 = acc1[i];
                o1.x *= nm; o1.y *= nm; o1.z *= nm; o1.w *= nm;
                C4[(size_t)(s0 + 4) * slab + (size_t)r * 4 + w0i] = o1;
            }
        }
    }
}

// ---------- Column-sliced gather-aggregate, serial edges per 8-lane group ----------
// feat is slice-major (F/16 slabs of [nnodes x 16] floats). slice = blockIdx.x % NSLICE
// rides the round-robin block->XCD dispatch so each XCD's L2 caches one 3.2 MB slab.
// An 8-lane group owns one (node, slice): lane holds float2 of the 16-col slice,
// loops the node's in-edges serially (unrolled x4), no cross-lane reduction.
// Output row-major: out[node, slice*16 .. slice*16+15].
template <int F, bool RELU>
__global__ __launch_bounds__(256) void aggregate_sliced(const float* __restrict__ feat,
                                                        const int* __restrict__ rowptr,
                                                        const int* __restrict__ esrc,
                                                        const float* __restrict__ norm,
                                                        const float* __restrict__ b,
                                                        float* __restrict__ out,
                                                        int nnodes, int nchunks) {
    constexpr int NSLICE = F / 16;
    const int slice = blockIdx.x % NSLICE;
    const int chunk = blockIdx.x / NSLICE;
    const int span  = (nnodes + nchunks - 1) / nchunks;
    const int nbeg  = chunk * span;
    const int nend  = min(nnodes, nbeg + span);

    const int grp = threadIdx.x >> 3;   // 32 groups per block
    const int l2  = threadIdx.x & 7;    // float2 lane within 16-col slice

    const float2* __restrict__ slab2 =
        reinterpret_cast<const float2*>(feat) + (size_t)slice * nnodes * 8;
    const float2 bb = reinterpret_cast<const float2*>(b)[slice * 8 + l2];

    for (int node = nbeg + grp; node < nend; node += 32) {
        const int beg = rowptr[node];
        const int end = rowptr[node + 1];

        float2 a0 = make_float2(0.f, 0.f), a1 = a0, a2 = a0, a3 = a0;
        int e = beg;
        for (; e + 3 < end; e += 4) {
            int s0 = esrc[e + 0];
            int s1 = esrc[e + 1];
            int s2 = esrc[e + 2];
            int s3 = esrc[e + 3];
            float2 v0 = slab2[(size_t)s0 * 8 + l2];
            float2 v1 = slab2[(size_t)s1 * 8 + l2];
            float2 v2 = slab2[(size_t)s2 * 8 + l2];
            float2 v3 = slab2[(size_t)s3 * 8 + l2];
            a0.x += v0.x; a0.y += v0.y;
            a1.x += v1.x; a1.y += v1.y;
            a2.x += v2.x; a2.y += v2.y;
            a3.x += v3.x; a3.y += v3.y;
        }
        for (; e < end; ++e) {
            int s0 = esrc[e];
            float2 v0 = slab2[(size_t)s0 * 8 + l2];
            a0.x += v0.x; a0.y += v0.y;
        }
        const float nm = norm[node];
        float ox = ((a0.x + a1.x) + (a2.x + a3.x)) * nm + bb.x;
        float oy = ((a0.y + a1.y) + (a2.y + a3.y)) * nm + bb.y;
        if (RELU) { ox = fmaxf(ox, 0.f); oy = fmaxf(oy, 0.f); }
        reinterpret_cast<float2*>(out)[(size_t)node * (F / 2) + slice * 8 + l2] =
            make_float2(ox, oy);
    }
}

extern "C" void kernel_launch(void* const* d_in, const int* in_sizes, int n_in,
                              void* d_out, int out_size, void* d_ws, size_t ws_size,
                              hipStream_t stream) {
    const float* features = (const float*)d_in[0];
    const int*   src      = (const int*)d_in[1];
    const int*   dst      = (const int*)d_in[2];
    const float* W1 = (const float*)d_in[3];
    const float* b1 = (const float*)d_in[4];
    const float* W2 = (const float*)d_in[5];
    const float* b2 = (const float*)d_in[6];
    const float* W3 = (const float*)d_in[7];
    const float* b3 = (const float*)d_in[8];
    float* out = (float*)d_out;

    auto align256 = [](size_t x) { return (x + 255) / 256 * 256; };
    char* ws = (char*)d_ws;
    size_t off = 0;
    float* norm     = (float*)(ws + off); off += align256((size_t)N_NODES * 4);
    int*   cnt      = (int*)(ws + off);   off += align256((size_t)N_NODES * 4);
    int*   cursor   = (int*)(ws + off);   off += align256((size_t)N_NODES * 4);
    int*   rowptr   = (int*)(ws + off);   off += align256(((size_t)N_NODES + 1) * 4);
    int*   partials = (int*)(ws + off);   off += align256((size_t)SCAN_NB * 4);
    int*   esrc     = (int*)(ws + off);   off += align256((size_t)N_EDGES * 4);
    float* buf0     = (float*)(ws + off); off += (size_t)N_NODES * 128 * 4;
    float* buf1     = (float*)(ws + off);

    const int gemm_blocks = (N_NODES + 127) / 128;
    const int edge_blocks = (N_EDGES + 255) / 256;
    const int chunks128 = 256;   // 256*8 = 2048 blocks
    const int chunks64  = 512;   // 512*4 = 2048 blocks

    // ---- CSR build + norm ----
    hipMemsetAsync(cnt, 0, (size_t)N_NODES * 4, stream);
    count_kernel<<<edge_blocks, 256, 0, stream>>>(dst, cnt, N_EDGES);
    scanA_kernel<<<SCAN_NB, 256, 0, stream>>>(cnt, partials, N_NODES);
    scanB_kernel<<<1, 256, 0, stream>>>(partials, SCAN_NB);
    scanC_kernel<<<SCAN_NB, 256, 0, stream>>>(cnt, partials, rowptr, cursor, norm, N_NODES);
    fill_kernel<<<edge_blocks, 256, 0, stream>>>(src, dst, cursor, esrc, N_EDGES);

    // ---- Layer 1 ----
    gemm_rownorm<128><<<gemm_blocks, 256, 0, stream>>>(features, W1, norm, buf0, N_NODES);
    aggregate_sliced<128, true><<<chunks128 * 8, 256, 0, stream>>>(buf0, rowptr, esrc, norm, b1, buf1, N_NODES, chunks128);

    // ---- Layer 2 ----
    gemm_rownorm<128><<<gemm_blocks, 256, 0, stream>>>(buf1, W2, norm, buf0, N_NODES);
    aggregate_sliced<128, true><<<chunks128 * 8, 256, 0, stream>>>(buf0, rowptr, esrc, norm, b2, buf1, N_NODES, chunks128);

    // ---- Layer 3 (64 cols) ----
    gemm_rownorm<64><<<gemm_blocks, 256, 0, stream>>>(buf1, W3, norm, buf0, N_NODES);
    aggregate_sliced<64, false><<<chunks64 * 4, 256, 0, stream>>>(buf0, rowptr, esrc, norm, b3, out, N_NODES, chunks64);
}